// Round 4
// baseline (470.154 us; speedup 1.0000x reference)
//
#include <hip/hip_runtime.h>

// Fused SpatialTransformer composed-flow kernel.
// out[0 : DHW]          = deform_2_img  (src warped by out_flow, align_corners=True)
// out[DHW : 4*DHW]      = out_flow      (flow1 warped by flow2 (align_corners=False) + flow2)
// Channel order of flow arrays: ch0 <-> z(D), ch1 <-> y(H), ch2 <-> x(W).

__global__ __launch_bounds__(256) void st_fused_kernel(
    const float* __restrict__ src,
    const float* __restrict__ flow1,
    const float* __restrict__ flow2,
    const float* __restrict__ range_flow,
    float* __restrict__ out,
    int D, int H, int W)
{
    const int DHW = D * H * W;
    int i = blockIdx.x * 256 + threadIdx.x;
    if (i >= DHW) return;

    const int x = i % W;
    const int t = i / W;
    const int y = t % H;
    const int z = t / H;

    const float rf = range_flow[0];

    // flow2 at this voxel (coalesced loads)
    const float f2z = flow2[i];
    const float f2y = flow2[DHW + i];
    const float f2x = flow2[2 * DHW + i];

    // ---- Stage 1: sample flow1 at grid + flow2*rf, align_corners=False ----
    // ix = xloc * W/(W-1) - 0.5  (derived from normalize->unnormalize chain)
    const float sx = (float)W / (float)(W - 1);
    const float sy = (float)H / (float)(H - 1);
    const float sz = (float)D / (float)(D - 1);

    const float ix = ((float)x + f2x * rf) * sx - 0.5f;
    const float iy = ((float)y + f2y * rf) * sy - 0.5f;
    const float iz = ((float)z + f2z * rf) * sz - 0.5f;

    const int x0 = (int)floorf(ix);
    const int y0 = (int)floorf(iy);
    const int z0 = (int)floorf(iz);
    const float fx = ix - (float)x0;
    const float fy = iy - (float)y0;
    const float fz = iz - (float)z0;

    float acc0 = 0.f, acc1 = 0.f, acc2 = 0.f;
#pragma unroll
    for (int dz = 0; dz < 2; ++dz) {
        const int zc = z0 + dz;
        if ((unsigned)zc >= (unsigned)D) continue;
        const float wz = dz ? fz : (1.f - fz);
#pragma unroll
        for (int dy = 0; dy < 2; ++dy) {
            const int yc = y0 + dy;
            if ((unsigned)yc >= (unsigned)H) continue;
            const float wy = dy ? fy : (1.f - fy);
#pragma unroll
            for (int dx = 0; dx < 2; ++dx) {
                const int xc = x0 + dx;
                if ((unsigned)xc >= (unsigned)W) continue;
                const float wx = dx ? fx : (1.f - fx);
                const float w = wx * wy * wz;
                const int base = (zc * H + yc) * W + xc;
                acc0 += w * flow1[base];
                acc1 += w * flow1[DHW + base];
                acc2 += w * flow1[2 * DHW + base];
            }
        }
    }

    // ---- out_flow = warped flow1 + flow2 ----
    const float of0 = acc0 + f2z;   // z-displacement channel
    const float of1 = acc1 + f2y;   // y
    const float of2 = acc2 + f2x;   // x

    out[DHW + i]     = of0;
    out[2 * DHW + i] = of1;
    out[3 * DHW + i] = of2;

    // ---- Stage 2: sample src at grid + out_flow*rf, align_corners=True ----
    // normalize(align_corners=True) then unnorm(align_corners=True) is identity:
    const float jx = (float)x + of2 * rf;
    const float jy = (float)y + of1 * rf;
    const float jz = (float)z + of0 * rf;

    const int u0 = (int)floorf(jx);
    const int v0 = (int)floorf(jy);
    const int w0 = (int)floorf(jz);
    const float gx = jx - (float)u0;
    const float gy = jy - (float)v0;
    const float gz = jz - (float)w0;

    float accs = 0.f;
#pragma unroll
    for (int dz = 0; dz < 2; ++dz) {
        const int zc = w0 + dz;
        if ((unsigned)zc >= (unsigned)D) continue;
        const float wz = dz ? gz : (1.f - gz);
#pragma unroll
        for (int dy = 0; dy < 2; ++dy) {
            const int yc = v0 + dy;
            if ((unsigned)yc >= (unsigned)H) continue;
            const float wy = dy ? gy : (1.f - gy);
#pragma unroll
            for (int dx = 0; dx < 2; ++dx) {
                const int xc = u0 + dx;
                if ((unsigned)xc >= (unsigned)W) continue;
                const float wx = dx ? gx : (1.f - gx);
                accs += (wx * wy * wz) * src[(zc * H + yc) * W + xc];
            }
        }
    }

    out[i] = accs;
}

extern "C" void kernel_launch(void* const* d_in, const int* in_sizes, int n_in,
                              void* d_out, int out_size, void* d_ws, size_t ws_size,
                              hipStream_t stream) {
    const float* src        = (const float*)d_in[0];
    const float* flow1      = (const float*)d_in[1];
    const float* flow2      = (const float*)d_in[2];
    const float* range_flow = (const float*)d_in[3];
    float* out = (float*)d_out;

    const int D = 160, H = 192, W = 224;
    const int DHW = D * H * W;
    const int blocks = (DHW + 255) / 256;
    st_fused_kernel<<<blocks, 256, 0, stream>>>(src, flow1, flow2, range_flow, out, D, H, W);
}

// Round 5
// 256.518 us; speedup vs baseline: 1.8328x; 1.8328x over previous
//
#include <hip/hip_runtime.h>

// Fused SpatialTransformer composed-flow kernel (branchless gathers).
// out[0 : DHW]     = deform_2_img  (src warped by out_flow, align_corners=True)
// out[DHW : 4*DHW] = out_flow      (flow1 warped by flow2 (align_corners=False) + flow2)
// Channel order: ch0 <-> z(D), ch1 <-> y(H), ch2 <-> x(W).

constexpr int kD = 160, kH = 192, kW = 224;
constexpr int kDHW = kD * kH * kW;

__global__ __launch_bounds__(256) void st_fused_kernel(
    const float* __restrict__ src,
    const float* __restrict__ flow1,
    const float* __restrict__ flow2,
    const float* __restrict__ range_flow,
    float* __restrict__ out)
{
    const int i = blockIdx.x * 256 + threadIdx.x;
    if (i >= kDHW) return;

    const int x = i % kW;
    const int t = i / kW;
    const int y = t % kH;
    const int z = t / kH;

    const float rf = range_flow[0];

    // flow2 at this voxel (coalesced)
    const float f2z = flow2[i];
    const float f2y = flow2[kDHW + i];
    const float f2x = flow2[2 * kDHW + i];

    // ---- Stage 1: sample flow1 at grid + flow2*rf, align_corners=False ----
    // normalize->unnormalize chain collapses to: ix = xloc * W/(W-1) - 0.5
    constexpr float SX = (float)kW / (float)(kW - 1);
    constexpr float SY = (float)kH / (float)(kH - 1);
    constexpr float SZ = (float)kD / (float)(kD - 1);

    const float ix = ((float)x + f2x * rf) * SX - 0.5f;
    const float iy = ((float)y + f2y * rf) * SY - 0.5f;
    const float iz = ((float)z + f2z * rf) * SZ - 0.5f;

    const float fx0 = floorf(ix), fy0 = floorf(iy), fz0 = floorf(iz);
    const int x0 = (int)fx0, y0 = (int)fy0, z0 = (int)fz0;
    const float fx = ix - fx0, fy = iy - fy0, fz = iz - fz0;

    // per-axis weights with zeros-padding folded in (branchless)
    const float wx0 = (1.f - fx) * (((unsigned)x0       < (unsigned)kW) ? 1.f : 0.f);
    const float wx1 = fx         * (((unsigned)(x0 + 1) < (unsigned)kW) ? 1.f : 0.f);
    const float wy0 = (1.f - fy) * (((unsigned)y0       < (unsigned)kH) ? 1.f : 0.f);
    const float wy1 = fy         * (((unsigned)(y0 + 1) < (unsigned)kH) ? 1.f : 0.f);
    const float wz0 = (1.f - fz) * (((unsigned)z0       < (unsigned)kD) ? 1.f : 0.f);
    const float wz1 = fz         * (((unsigned)(z0 + 1) < (unsigned)kD) ? 1.f : 0.f);

    const int xc0 = min(max(x0, 0), kW - 1), xc1 = min(max(x0 + 1, 0), kW - 1);
    const int yc0 = min(max(y0, 0), kH - 1), yc1 = min(max(y0 + 1, 0), kH - 1);
    const int zc0 = min(max(z0, 0), kD - 1), zc1 = min(max(z0 + 1, 0), kD - 1);

    // 4 row bases
    const int r00 = (zc0 * kH + yc0) * kW;
    const int r01 = (zc0 * kH + yc1) * kW;
    const int r10 = (zc1 * kH + yc0) * kW;
    const int r11 = (zc1 * kH + yc1) * kW;

    // 8 corner weights
    const float w000 = wz0 * wy0 * wx0, w001 = wz0 * wy0 * wx1;
    const float w010 = wz0 * wy1 * wx0, w011 = wz0 * wy1 * wx1;
    const float w100 = wz1 * wy0 * wx0, w101 = wz1 * wy0 * wx1;
    const float w110 = wz1 * wy1 * wx0, w111 = wz1 * wy1 * wx1;

    const float* __restrict__ f1a = flow1;
    const float* __restrict__ f1b = flow1 + kDHW;
    const float* __restrict__ f1c = flow1 + 2 * kDHW;

    // issue all 24 gathers back-to-back (no intervening uses -> one waitcnt window)
    const float a000 = f1a[r00 + xc0], a001 = f1a[r00 + xc1];
    const float a010 = f1a[r01 + xc0], a011 = f1a[r01 + xc1];
    const float a100 = f1a[r10 + xc0], a101 = f1a[r10 + xc1];
    const float a110 = f1a[r11 + xc0], a111 = f1a[r11 + xc1];

    const float b000 = f1b[r00 + xc0], b001 = f1b[r00 + xc1];
    const float b010 = f1b[r01 + xc0], b011 = f1b[r01 + xc1];
    const float b100 = f1b[r10 + xc0], b101 = f1b[r10 + xc1];
    const float b110 = f1b[r11 + xc0], b111 = f1b[r11 + xc1];

    const float c000 = f1c[r00 + xc0], c001 = f1c[r00 + xc1];
    const float c010 = f1c[r01 + xc0], c011 = f1c[r01 + xc1];
    const float c100 = f1c[r10 + xc0], c101 = f1c[r10 + xc1];
    const float c110 = f1c[r11 + xc0], c111 = f1c[r11 + xc1];

    const float acc0 = w000 * a000 + w001 * a001 + w010 * a010 + w011 * a011
                     + w100 * a100 + w101 * a101 + w110 * a110 + w111 * a111;
    const float acc1 = w000 * b000 + w001 * b001 + w010 * b010 + w011 * b011
                     + w100 * b100 + w101 * b101 + w110 * b110 + w111 * b111;
    const float acc2 = w000 * c000 + w001 * c001 + w010 * c010 + w011 * c011
                     + w100 * c100 + w101 * c101 + w110 * c110 + w111 * c111;

    // ---- out_flow = warped flow1 + flow2 ----
    const float of0 = acc0 + f2z;   // z
    const float of1 = acc1 + f2y;   // y
    const float of2 = acc2 + f2x;   // x

    out[kDHW + i]     = of0;
    out[2 * kDHW + i] = of1;
    out[3 * kDHW + i] = of2;

    // ---- Stage 2: sample src at grid + out_flow*rf, align_corners=True ----
    // normalize(True) then unnorm(True) is the identity map:
    const float jx = (float)x + of2 * rf;
    const float jy = (float)y + of1 * rf;
    const float jz = (float)z + of0 * rf;

    const float gx0f = floorf(jx), gy0f = floorf(jy), gz0f = floorf(jz);
    const int u0 = (int)gx0f, v0 = (int)gy0f, q0 = (int)gz0f;
    const float gx = jx - gx0f, gy = jy - gy0f, gz = jz - gz0f;

    const float vx0 = (1.f - gx) * (((unsigned)u0       < (unsigned)kW) ? 1.f : 0.f);
    const float vx1 = gx         * (((unsigned)(u0 + 1) < (unsigned)kW) ? 1.f : 0.f);
    const float vy0 = (1.f - gy) * (((unsigned)v0       < (unsigned)kH) ? 1.f : 0.f);
    const float vy1 = gy         * (((unsigned)(v0 + 1) < (unsigned)kH) ? 1.f : 0.f);
    const float vz0 = (1.f - gz) * (((unsigned)q0       < (unsigned)kD) ? 1.f : 0.f);
    const float vz1 = gz         * (((unsigned)(q0 + 1) < (unsigned)kD) ? 1.f : 0.f);

    const int uc0 = min(max(u0, 0), kW - 1), uc1 = min(max(u0 + 1, 0), kW - 1);
    const int vc0 = min(max(v0, 0), kH - 1), vc1 = min(max(v0 + 1, 0), kH - 1);
    const int qc0 = min(max(q0, 0), kD - 1), qc1 = min(max(q0 + 1, 0), kD - 1);

    const int s00 = (qc0 * kH + vc0) * kW;
    const int s01 = (qc0 * kH + vc1) * kW;
    const int s10 = (qc1 * kH + vc0) * kW;
    const int s11 = (qc1 * kH + vc1) * kW;

    const float p000 = src[s00 + uc0], p001 = src[s00 + uc1];
    const float p010 = src[s01 + uc0], p011 = src[s01 + uc1];
    const float p100 = src[s10 + uc0], p101 = src[s10 + uc1];
    const float p110 = src[s11 + uc0], p111 = src[s11 + uc1];

    const float accs = (vz0 * vy0 * vx0) * p000 + (vz0 * vy0 * vx1) * p001
                     + (vz0 * vy1 * vx0) * p010 + (vz0 * vy1 * vx1) * p011
                     + (vz1 * vy0 * vx0) * p100 + (vz1 * vy0 * vx1) * p101
                     + (vz1 * vy1 * vx0) * p110 + (vz1 * vy1 * vx1) * p111;

    out[i] = accs;
}

extern "C" void kernel_launch(void* const* d_in, const int* in_sizes, int n_in,
                              void* d_out, int out_size, void* d_ws, size_t ws_size,
                              hipStream_t stream) {
    const float* src        = (const float*)d_in[0];
    const float* flow1      = (const float*)d_in[1];
    const float* flow2      = (const float*)d_in[2];
    const float* range_flow = (const float*)d_in[3];
    float* out = (float*)d_out;

    const int blocks = (kDHW + 255) / 256;
    st_fused_kernel<<<blocks, 256, 0, stream>>>(src, flow1, flow2, range_flow, out);
}